// Round 2
// baseline (47.294 us; speedup 1.0000x reference)
//
#include <hip/hip_runtime.h>
#include <math.h>

#define CLS_NUM 1000
#define FEAT 512

// One wave (64 lanes) per sample: 512 floats = 64 lanes x 2 float4.
// Fused pass: per-class dist-sum + per-class count via global atomics
// (1000 bins, ~65 adds/bin, fire-and-forget -> hidden under HBM stream).
__global__ __launch_bounds__(256) void center_loss_dist(
    const float* __restrict__ xs,
    const void* __restrict__ ys_raw,
    const float* __restrict__ center,
    float* __restrict__ distsum,
    unsigned int* __restrict__ count,
    int n)
{
    // Detect int64 vs int32 labels: for int64 (little-endian) the high
    // 32-bit word of each element is 0 and low word < 1000. For int32,
    // odd words are random labels; all-zero across 16 slots ~ 1e-48.
    const int* y32 = (const int*)ys_raw;
    bool is64 = true;
    #pragma unroll
    for (int k = 0; k < 16; ++k) {
        int lo = y32[2 * k], hi = y32[2 * k + 1];
        if (hi != 0 || (unsigned)lo >= (unsigned)CLS_NUM) is64 = false;
    }
    const long long* y64 = (const long long*)ys_raw;

    const int lane  = threadIdx.x & 63;
    const int wave  = (int)((blockIdx.x * blockDim.x + threadIdx.x) >> 6);
    const int nwave = (int)((gridDim.x * blockDim.x) >> 6);

    for (int i = wave; i < n; i += nwave) {
        const int y = is64 ? (int)y64[i] : y32[i];
        const float4* xp = (const float4*)(xs + (size_t)i * FEAT);
        const float4* cp = (const float4*)(center + (size_t)y * FEAT);
        // Fully coalesced: lane l reads float4 #l and #(l+64) of the row.
        float4 x0 = xp[lane];
        float4 x1 = xp[lane + 64];
        float4 c0 = cp[lane];
        float4 c1 = cp[lane + 64];
        float d, s = 0.f;
        d = x0.x - c0.x; s += d * d;
        d = x0.y - c0.y; s += d * d;
        d = x0.z - c0.z; s += d * d;
        d = x0.w - c0.w; s += d * d;
        d = x1.x - c1.x; s += d * d;
        d = x1.y - c1.y; s += d * d;
        d = x1.z - c1.z; s += d * d;
        d = x1.w - c1.w; s += d * d;
        #pragma unroll
        for (int off = 32; off; off >>= 1)
            s += __shfl_xor(s, off, 64);
        if (lane == 0) {
            atomicAdd(&distsum[y], sqrtf(s));
            atomicAdd(&count[y], 1u);
        }
    }
}

// out = sum_c distsum[c] / count[c]   (count>0 guard; absent classes add 0)
__global__ __launch_bounds__(256) void center_loss_final(
    const float* __restrict__ distsum,
    const unsigned int* __restrict__ count,
    float* __restrict__ out)
{
    float s = 0.f;
    for (int c = threadIdx.x; c < CLS_NUM; c += 256) {
        unsigned n = count[c];
        if (n) s += distsum[c] / (float)n;
    }
    #pragma unroll
    for (int off = 32; off; off >>= 1)
        s += __shfl_xor(s, off, 64);
    __shared__ float wsum[4];
    if ((threadIdx.x & 63) == 0) wsum[threadIdx.x >> 6] = s;
    __syncthreads();
    if (threadIdx.x == 0)
        out[0] = wsum[0] + wsum[1] + wsum[2] + wsum[3];
}

extern "C" void kernel_launch(void* const* d_in, const int* in_sizes, int n_in,
                              void* d_out, int out_size, void* d_ws, size_t ws_size,
                              hipStream_t stream)
{
    const float* xs     = (const float*)d_in[0];
    const void*  ys     = d_in[1];
    const float* center = (const float*)d_in[2];
    float* out = (float*)d_out;

    // ws layout: [0,4000) distsum floats ; [4096, 8096) counts
    float* distsum       = (float*)d_ws;
    unsigned int* count  = (unsigned int*)((char*)d_ws + 4096);
    hipMemsetAsync(d_ws, 0, 8192, stream);

    const int n = in_sizes[1];  // number of samples (ys element count)

    center_loss_dist<<<2048, 256, 0, stream>>>(xs, ys, center, distsum, count, n);
    center_loss_final<<<1, 256, 0, stream>>>(distsum, count, out);
}